// Round 2
// 542.680 us; speedup vs baseline: 1.0485x; 1.0485x over previous
//
#include <hip/hip_runtime.h>

// Convert2Image: out[b,h,w,:] = lstm[b, slic[b,h,w]-1, :]
// B=4, S=256, C=128, H=W=512. fp32 in/out.
// Streaming gather: 512 MiB written, ~4.5 MiB effectively read (cached).
// v2b: 4 float4 per thread, phase-split loads for 4-deep MLP, contiguous
//      16 KiB of output per block, non-temporal stores (out is never re-read,
//      keep the 512 KiB lstm table resident in L2).
//      Fix vs v2: __builtin_nontemporal_store needs a NATIVE vector type,
//      not HIP_vector_type<float,4> — use ext_vector_type(4) alias.
// All dims are powers of two: C/4 = 32 = 2^5, H*W = 2^18, S = 2^8.

typedef float f32x4 __attribute__((ext_vector_type(4)));

constexpr int C4      = 32;      // C/4 float4 per pixel
constexpr int LOG_C4  = 5;
constexpr int LOG_HW  = 18;      // H*W = 262144
constexpr int LOG_S   = 8;       // S = 256
constexpr int UNROLL  = 4;       // float4 per thread
constexpr int BLK     = 256;

__global__ __launch_bounds__(BLK)
void convert2image_kernel(const f32x4* __restrict__ lstm,  // [B*S*C4]
                          const int*   __restrict__ slic,  // [B*H*W], 1-based
                          f32x4*       __restrict__ out,   // [B*H*W*C4]
                          int n4)
{
    // Block covers BLK*UNROLL = 1024 consecutive float4 = 32 pixels = 16 KiB out.
    // All 32 pixels' slic ids live in one 128 B cache line.
    int base = blockIdx.x * (BLK * UNROLL) + threadIdx.x;

    int  src[UNROLL];
    bool ok [UNROLL];

    // Phase 1: issue all slic loads (independent) and compute gather addresses.
    #pragma unroll
    for (int u = 0; u < UNROLL; ++u) {
        int i = base + u * BLK;
        ok[u] = (i < n4);
        if (ok[u]) {
            int c4  = i & (C4 - 1);          // float4 index within channel row
            int pix = i >> LOG_C4;           // linear pixel over B*H*W
            int b   = pix >> LOG_HW;         // batch
            int seg = slic[pix] - 1;         // 0-based segment id in [0, S)
            src[u]  = (((b << LOG_S) + seg) << LOG_C4) + c4;
        }
    }

    // Phase 2: issue all gathers, then stream the stores (non-temporal:
    // out is write-once, don't let 537 MB of stores thrash L2).
    #pragma unroll
    for (int u = 0; u < UNROLL; ++u) {
        if (ok[u]) {
            f32x4 v = lstm[src[u]];
            __builtin_nontemporal_store(v, &out[base + u * BLK]);
        }
    }
}

extern "C" void kernel_launch(void* const* d_in, const int* in_sizes, int n_in,
                              void* d_out, int out_size, void* d_ws, size_t ws_size,
                              hipStream_t stream) {
    const f32x4* lstm = (const f32x4*)d_in[0];   // graph_lstm_output [4,256,128] f32
    const int*   slic = (const int*)d_in[1];     // slic_output [4,512,512] i32
    f32x4*       out  = (f32x4*)d_out;           // [4,512,512,128] f32

    int n4 = out_size / 4;                       // 33,554,432 float4 elements
    int blocks = (n4 + BLK * UNROLL - 1) / (BLK * UNROLL);  // 32,768 blocks, no tail
    convert2image_kernel<<<blocks, BLK, 0, stream>>>(lstm, slic, out, n4);
}

// Round 3
// 520.121 us; speedup vs baseline: 1.0940x; 1.0434x over previous
//
#include <hip/hip_runtime.h>

// Convert2Image: out[b,h,w,:] = lstm[b, slic[b,h,w]-1, :]
// B=4, S=256, C=128, H=W=512. fp32 in/out.
// 512 MiB written, ~4.5 MiB effectively read (cache-absorbed).
//
// v3: persistent grid-stride kernel with cross-tile software pipeline.
//   - 2048 blocks x 256 threads, each block owns n_tiles/2048 tiles.
//   - Per tile: 8 float4/thread (8 KiB/wave burst).
//   - Pipeline: issue gathers(t) -> issue slic loads(t+1) [independent]
//     -> wait gathers only (FIFO vmcnt leaves slic in flight) -> nt-store(t)
//     -> compute addrs(t+1). Store pipe never waits on the slic stream.
//   - nt stores: out is write-once; keep the 512 KiB lstm table L2-resident.
// All dims are powers of two: C/4 = 32 = 2^5, H*W = 2^18, S = 2^8.

typedef float f32x4 __attribute__((ext_vector_type(4)));

constexpr int C4       = 32;     // C/4 float4 per pixel
constexpr int LOG_C4   = 5;
constexpr int LOG_HW   = 18;     // H*W = 262144
constexpr int LOG_S    = 8;      // S = 256
constexpr int UNROLL   = 8;      // float4 per thread per tile
constexpr int BLK      = 256;
constexpr int TILE     = BLK * UNROLL;   // 2048 float4 = 64 pixels = 32 KiB out
constexpr int LOG_TILE = 11;
constexpr int MAXGRID  = 2048;   // 8 blocks/CU; grid-stride the rest

__global__ __launch_bounds__(BLK)
void convert2image_kernel(const f32x4* __restrict__ lstm,  // [B*S*C4]
                          const int*   __restrict__ slic,  // [B*H*W], 1-based
                          f32x4*       __restrict__ out,   // [B*H*W*C4]
                          int n4)
{
    const int n_tiles = n4 >> LOG_TILE;
    const int t       = threadIdx.x;

    if ((int)blockIdx.x < n_tiles) {
        int tile   = blockIdx.x;
        int stride = gridDim.x;
        int base   = tile * TILE + t;

        // ---- prologue: slic + addresses for first tile ----
        int src[UNROLL];
        {
            int sg[UNROLL];
            #pragma unroll
            for (int u = 0; u < UNROLL; ++u)
                sg[u] = slic[(base + u * BLK) >> LOG_C4];
            #pragma unroll
            for (int u = 0; u < UNROLL; ++u) {
                int i  = base + u * BLK;
                int c4 = i & (C4 - 1);
                int b  = i >> (LOG_C4 + LOG_HW);
                src[u] = (((b << LOG_S) + (sg[u] - 1)) << LOG_C4) + c4;
            }
        }

        for (;;) {
            const int  next  = tile + stride;
            const bool more  = next < n_tiles;
            const int  nbase = next * TILE + t;

            // 1) issue gathers for current tile (oldest in vmcnt FIFO)
            f32x4 v[UNROLL];
            #pragma unroll
            for (int u = 0; u < UNROLL; ++u)
                v[u] = lstm[src[u]];

            // 2) issue slic loads for NEXT tile — independent of the gathers,
            //    younger in the FIFO, so waiting for gathers leaves them in flight
            int nsg[UNROLL];
            if (more) {
                #pragma unroll
                for (int u = 0; u < UNROLL; ++u)
                    nsg[u] = slic[(nbase + u * BLK) >> LOG_C4];
            }

            // 3) store current tile (compiler waits vmcnt for gathers only)
            #pragma unroll
            for (int u = 0; u < UNROLL; ++u)
                __builtin_nontemporal_store(v[u], &out[base + u * BLK]);

            if (!more) break;

            // 4) compute next tile's gather addresses (slic wait overlaps stores)
            #pragma unroll
            for (int u = 0; u < UNROLL; ++u) {
                int i  = nbase + u * BLK;
                int c4 = i & (C4 - 1);
                int b  = i >> (LOG_C4 + LOG_HW);
                src[u] = (((b << LOG_S) + (nsg[u] - 1)) << LOG_C4) + c4;
            }
            base = nbase;
            tile = next;
        }
    }

    // ---- tail (n4 not a multiple of TILE; no-op for this shape) ----
    if (blockIdx.x == 0) {
        for (int i = (n_tiles << LOG_TILE) + t; i < n4; i += BLK) {
            int c4  = i & (C4 - 1);
            int pix = i >> LOG_C4;
            int b   = pix >> LOG_HW;
            int seg = slic[pix] - 1;
            f32x4 vv = lstm[(((b << LOG_S) + seg) << LOG_C4) + c4];
            __builtin_nontemporal_store(vv, &out[i]);
        }
    }
}

extern "C" void kernel_launch(void* const* d_in, const int* in_sizes, int n_in,
                              void* d_out, int out_size, void* d_ws, size_t ws_size,
                              hipStream_t stream) {
    const f32x4* lstm = (const f32x4*)d_in[0];   // graph_lstm_output [4,256,128] f32
    const int*   slic = (const int*)d_in[1];     // slic_output [4,512,512] i32
    f32x4*       out  = (f32x4*)d_out;           // [4,512,512,128] f32

    int n4      = out_size / 4;                  // 33,554,432 float4 elements
    int n_tiles = n4 >> LOG_TILE;                // 16,384 tiles
    int blocks  = n_tiles < MAXGRID ? (n_tiles > 0 ? n_tiles : 1) : MAXGRID;
    convert2image_kernel<<<blocks, BLK, 0, stream>>>(lstm, slic, out, n4);
}